// Round 15
// baseline (186.997 us; speedup 1.0000x reference)
//
#include <hip/hip_runtime.h>

#define TOKENS 8192
#define IN_F   4096
#define OUT_F  4096

#define BM 256
#define BN 256
#define BKB 128              // K-bytes per tile (= 2 mfma K-steps of 64)
#define NT (IN_F / BKB)      // 32 K-tiles
#define NI (NT / 2)          // 16 outer iterations (2 tiles each)

using int4v = __attribute__((ext_vector_type(4))) int;
typedef __attribute__((address_space(3))) char       lds_char_t;
typedef const __attribute__((address_space(1))) char glob_char_t;

// ---------------- pack int32 -> int8 (values already in [-128,127]) ----------------
__global__ void pack_i32_to_i8(const int* __restrict__ src, int* __restrict__ dst, int n4) {
    int stride = gridDim.x * blockDim.x;
    for (int i = blockIdx.x * blockDim.x + threadIdx.x; i < n4; i += stride) {
        int4v v = ((const int4v*)src)[i];
        dst[i] = (v.x & 0xff) | ((v.y & 0xff) << 8) | ((v.z & 0xff) << 16) | (v.w << 24);
    }
}

// ---------------- 256x256 i8 GEMM, 8-phase, FLATTENED read cadence (8/4 per phase) ----
// vs R8/R14 (134us, MfmaUtil 46%): R8's per-wave read bursts were 12/8/4/0 — the
// 12-read phases put 96 b128 = 1152cy on the CU LDS pipe, exceeding the 653cy MFMA
// burst, so reads could not drain under compute; wave WKs stalled mid-phase
// (serial prefix ~600cy => phase 1250, MfmaUtil 653/1250=46% as measured).
// FIX: MFMA quadrant order (a03,b01)->(a03,b23)->(a47,b01)->(a47,b23) and a47
// reads split k0/k1 => reads per phase = 8,4,8,4,... (max 64/CU = 768cy ~ matrix).
// Ledger (per wave, verified): WK(8) odd / WK(4) even phases drains all older
// reads; P2/P6 end add lgkmcnt(0) own-drain (their a47k1 reads target the region
// staged next phase). VM(4)@P2/P6 confirms next A-tile (staged 2-3 phases ago),
// VM(2)@P3/P7 confirms next B-tile. All drains BEFORE the barrier (R12 lesson:
// vmcnt is per-wave, s_barrier does not wait memory). Staging rotation, swizzles,
// chunked XCD map, epilogue identical to R14 (verified).
__global__ __launch_bounds__(512, 2) void qgemm_i8(
    const signed char* __restrict__ A,   // [M][K] int8
    const signed char* __restrict__ Bw,  // [N][K] int8
    const int*   __restrict__ bias,
    const float* __restrict__ wscale,
    const float* __restrict__ p_si, const float* __restrict__ p_so, const float* __restrict__ p_zp,
    int* __restrict__ C)
{
    constexpr int N = OUT_F, K = IN_F;
    constexpr int NBN = N / BN;  // 16

    __shared__ __align__(16) signed char smem[131072];

    // Chunked XCD-aware mapping (grid 512 = 32 bm x 16 bn; XCD = bid & 7):
    int bid = blockIdx.x;
    int bm, bn;
    if (gridDim.x == 512) {
        int x = bid & 7;            // XCD
        int s = bid >> 3;           // 0..63 within XCD
        int r = s >> 5;             // round 0/1
        int u = s & 31;             // slot in chunk
        int c = x + 8 * r;          // chunk 0..15
        bm = (c & 7) * 4 + (u >> 3);
        bn = (c >> 3) * 8 + (u & 7);
    } else {
        int swz = bid;
        if ((gridDim.x & 7) == 0) { int cpx = gridDim.x >> 3; swz = (bid & 7) * cpx + (bid >> 3); }
        bm = swz / NBN; bn = swz - (swz / NBN) * NBN;
    }

    const int t = threadIdx.x, wid = t >> 6, l = t & 63;
    const int wr = wid >> 2, wc = wid & 3, lr = l & 15, lg = l >> 4;

    // ds_read offsets: frag (row, kk): byte = row*128 + ((kk*4+lg)^(lr&7))<<4
    const int k0off = ((lg       ^ (lr & 7)) << 4);
    const int k1off = (((4 + lg) ^ (lr & 7)) << 4);
    const int arow = (wr * 128 + lr) * 128;  // + m*2048
    const int brow = (wc * 64  + lr) * 128;  // + n*2048

    // staging: thread t writes LDS-linear o = e*8192 + t*16 within a half-tile
    const int srow = t >> 3;                                  // 0..63
    const int scol = (((t & 7) ^ ((t >> 3) & 7)) << 4);
    const signed char* gApl = A  + (size_t)(bm * BM + srow) * K + scol;
    const signed char* gBpl = Bw + (size_t)(bn * BN + srow) * K + scol;

#define STA(bufOff_, h_, tt_) do {                                                                 \
    __builtin_amdgcn_global_load_lds((glob_char_t*)(gApl + (size_t)((h_)*128      ) * K + (tt_)*BKB), \
        (lds_char_t*)smem + (bufOff_) + (h_)*16384 +        wid*1024, 16, 0, 0);                   \
    __builtin_amdgcn_global_load_lds((glob_char_t*)(gApl + (size_t)((h_)*128 + 64 ) * K + (tt_)*BKB), \
        (lds_char_t*)smem + (bufOff_) + (h_)*16384 + 8192 + wid*1024, 16, 0, 0);                   \
} while (0)
#define STB(bufOff_, h_, tt_) do {                                                                 \
    __builtin_amdgcn_global_load_lds((glob_char_t*)(gBpl + (size_t)((h_)*128      ) * K + (tt_)*BKB), \
        (lds_char_t*)smem + (bufOff_) + 32768 + (h_)*16384 +        wid*1024, 16, 0, 0);           \
    __builtin_amdgcn_global_load_lds((glob_char_t*)(gBpl + (size_t)((h_)*128 + 64 ) * K + (tt_)*BKB), \
        (lds_char_t*)smem + (bufOff_) + 32768 + (h_)*16384 + 8192 + wid*1024, 16, 0, 0);           \
} while (0)

    // LDS byte-offset bases (32-bit AS(3) addresses) — swizzle folded in
#define LDSOFF(x_) ((unsigned)(uintptr_t)((lds_char_t*)smem + (x_)))
    const unsigned aB0k0 = LDSOFF(arow + k0off);
    const unsigned aB0k1 = LDSOFF(arow + k1off);
    const unsigned aB1k0 = aB0k0 + 65536u;
    const unsigned aB1k1 = aB0k1 + 65536u;
    const unsigned bB0k0 = LDSOFF(32768 + brow + k0off);
    const unsigned bB0k1 = LDSOFF(32768 + brow + k1off);
    const unsigned bB1k0 = bB0k0 + 65536u;
    const unsigned bB1k1 = bB0k1 + 65536u;

#define DSR(dst_, base_, imm_) \
    asm volatile("ds_read_b128 %0, %1 offset:" #imm_ : "=&v"(dst_) : "v"(base_))

#define RD_A03(p0_, p1_) do { \
    DSR(a[0][0], p0_, 0);     DSR(a[0][1], p1_, 0);     \
    DSR(a[1][0], p0_, 2048);  DSR(a[1][1], p1_, 2048);  \
    DSR(a[2][0], p0_, 4096);  DSR(a[2][1], p1_, 4096);  \
    DSR(a[3][0], p0_, 6144);  DSR(a[3][1], p1_, 6144);  } while (0)
#define RD_A47K0(p0_) do { \
    DSR(a[4][0], p0_, 8192);  DSR(a[5][0], p0_, 10240); \
    DSR(a[6][0], p0_, 12288); DSR(a[7][0], p0_, 14336); } while (0)
#define RD_A47K1(p1_) do { \
    DSR(a[4][1], p1_, 8192);  DSR(a[5][1], p1_, 10240); \
    DSR(a[6][1], p1_, 12288); DSR(a[7][1], p1_, 14336); } while (0)
#define RD_B01(p0_, p1_) do { \
    DSR(b[0][0], p0_, 0);     DSR(b[0][1], p1_, 0);     \
    DSR(b[1][0], p0_, 2048);  DSR(b[1][1], p1_, 2048);  } while (0)
#define RD_B23(p0_, p1_) do { \
    DSR(b[2][0], p0_, 4096);  DSR(b[2][1], p1_, 4096);  \
    DSR(b[3][0], p0_, 6144);  DSR(b[3][1], p1_, 6144);  } while (0)

#define MF(mb_, nb_) do { _Pragma("unroll") for (int kk = 0; kk < 2; ++kk)                         \
    _Pragma("unroll") for (int mm = 0; mm < 4; ++mm)                                               \
    _Pragma("unroll") for (int nn = 0; nn < 2; ++nn)                                               \
        acc[(mb_)+mm][(nb_)+nn] = __builtin_amdgcn_mfma_i32_16x16x64_i8(                           \
            a[(mb_)+mm][kk], b[(nb_)+nn][kk], acc[(mb_)+mm][(nb_)+nn], 0, 0, 0); } while (0)

#define SP1 __builtin_amdgcn_s_setprio(1)
#define SP0 __builtin_amdgcn_s_setprio(0)
#define BAR __builtin_amdgcn_s_barrier()
#define VM(n_) asm volatile("s_waitcnt vmcnt(" #n_ ")" ::: "memory")
#define WK(n_) do { asm volatile("s_waitcnt lgkmcnt(" #n_ ")" ::: "memory"); \
                    __builtin_amdgcn_sched_barrier(0); } while (0)

    int4v acc[8][4] = {};
    int4v a[8][2], b[4][2];

    // ---- prologue: buf0 <- tile0 (A,B), buf1 <- tile1 (A); VM(4) confirms tile0;
    //      read a[0..3]k0k1 + b[0..1] of tile0 (12 reads; drained by P1's WK(8)).
    STA(0, 0, 0); STA(0, 1, 0); STB(0, 0, 0); STB(0, 1, 0);
    STA(65536, 0, 1); STA(65536, 1, 1);
    VM(4);
    BAR;
    RD_A03(aB0k0, aB0k1); RD_B01(bB0k0, bB0k1);

    // Phases (iteration i; buf0 = tile 2i, buf1 = 2i+1):
    //  P1: ST t1.B.h0 | rd b23(B0)+a47k0(A0) [8] | WK8 | MF(a03,b01)           | BAR
    //  P2: ST t1.B.h1 | rd a47k1(A0)         [4] | WK4 | MF(a03,b23) | WK0 VM4 | BAR
    //  P3: ST t2.A.h0 | rd a03(B1)           [8] | WK8 | MF(a47,b01) |     VM2 | BAR
    //  P4: ST t2.A.h1 | rd b01(B1)           [4] | WK4 | MF(a47,b23)           | BAR
    //  P5-P8: mirror with buf1 compute / buf0 staging.
#define ITER(i_, FULL_) do {                                                                       \
    const int t1 = 2*(i_)+1, t2 = 2*(i_)+2, t3 = 2*(i_)+3;                                         \
    /*P1*/ STB(65536, 0, t1); RD_B23(bB0k0, bB0k1); RD_A47K0(aB0k0);                               \
           WK(8); SP1; MF(0, 0); SP0;                BAR;                                          \
    /*P2*/ STB(65536, 1, t1); RD_A47K1(aB0k1);                                                     \
           WK(4); SP1; MF(0, 2); SP0; WK(0); VM(4);  BAR;                                          \
    /*P3*/ if (FULL_) STA(0, 0, t2); RD_A03(aB1k0, aB1k1);                                         \
           WK(8); SP1; MF(4, 0); SP0; VM(2);         BAR;                                          \
    /*P4*/ if (FULL_) STA(0, 1, t2); RD_B01(bB1k0, bB1k1);                                         \
           WK(4); SP1; MF(4, 2); SP0;                BAR;                                          \
    /*P5*/ if (FULL_) STB(0, 0, t2); RD_B23(bB1k0, bB1k1); RD_A47K0(aB1k0);                        \
           WK(8); SP1; MF(0, 0); SP0;                BAR;                                          \
    /*P6*/ if (FULL_) STB(0, 1, t2); RD_A47K1(aB1k1);                                              \
           WK(4); SP1; MF(0, 2); SP0; WK(0); VM(4);  BAR;                                          \
    /*P7*/ if (FULL_) { STA(65536, 0, t3); RD_A03(aB0k0, aB0k1); }                                 \
           WK(8); SP1; MF(4, 0); SP0; VM(2);         BAR;                                          \
    /*P8*/ if (FULL_) { STA(65536, 1, t3); RD_B01(bB0k0, bB0k1); }                                 \
           WK(4); SP1; MF(4, 2); SP0;                BAR;                                          \
} while (0)

    for (int i = 0; i < NI - 1; ++i) ITER(i, 1);
    ITER(NI - 1, 0);

#undef ITER
#undef WK
#undef VM
#undef BAR
#undef SP0
#undef SP1
#undef MF
#undef RD_B23
#undef RD_B01
#undef RD_A47K1
#undef RD_A47K0
#undef RD_A03
#undef DSR
#undef LDSOFF
#undef STB
#undef STA

    // ---- epilogue: y = clip(rint(scale[n]*(acc+bias[n]) + zp)), stored as int32 ----
    float si = p_si[0], so = p_so[0], z = p_zp[0];
    float rs = si / so;

    #pragma unroll
    for (int n = 0; n < 4; ++n) {
        int col = bn * BN + wc * 64 + n * 16 + lr;
        float sc = wscale[col] * rs;
        int   bs = bias[col];
        #pragma unroll
        for (int m = 0; m < 8; ++m) {
            int row = bm * BM + wr * 128 + m * 16 + lg * 4;
            #pragma unroll
            for (int r = 0; r < 4; ++r) {
                float y = sc * (float)(acc[m][n][r] + bs) + z;
                y = rintf(y);
                y = fminf(fmaxf(y, -128.0f), 127.0f);
                C[(size_t)(row + r) * N + col] = (int)y;
            }
        }
    }
}

// ---------------- fallback if workspace too small: naive but exact ----------------
__global__ void qgemm_naive(const int* __restrict__ qx, const int* __restrict__ qw,
                            const int* __restrict__ bias, const float* __restrict__ wscale,
                            const float* __restrict__ si, const float* __restrict__ so,
                            const float* __restrict__ zp, int* __restrict__ out) {
    int idx = blockIdx.x * blockDim.x + threadIdx.x;
    if (idx >= TOKENS * OUT_F) return;
    int row = idx / OUT_F, col = idx - row * OUT_F;
    const int4v* xa = (const int4v*)(qx + (size_t)row * IN_F);
    const int4v* wb = (const int4v*)(qw + (size_t)col * IN_F);
    int acc = 0;
    for (int k = 0; k < IN_F / 4; ++k) {
        int4v a = xa[k], b = wb[k];
        acc += a.x * b.x + a.y * b.y + a.z * b.z + a.w * b.w;
    }
    float y = wscale[col] * si[0] / so[0] * (float)(acc + bias[col]) + zp[0];
    y = fminf(fmaxf(rintf(y), -128.0f), 127.0f);
    out[idx] = (int)y;
}

extern "C" void kernel_launch(void* const* d_in, const int* in_sizes, int n_in,
                              void* d_out, int out_size, void* d_ws, size_t ws_size,
                              hipStream_t stream) {
    const int*   q_x    = (const int*)d_in[0];
    const int*   q_w    = (const int*)d_in[1];
    const int*   bias   = (const int*)d_in[2];
    const float* wscale = (const float*)d_in[3];
    const float* s_in   = (const float*)d_in[4];
    const float* s_out  = (const float*)d_in[5];
    const float* zp     = (const float*)d_in[6];
    int* out = (int*)d_out;

    const size_t needA = (size_t)TOKENS * IN_F;  // 32 MiB
    const size_t needB = (size_t)OUT_F * IN_F;   // 16 MiB

    if (ws_size >= needA + needB) {
        signed char* pA = (signed char*)d_ws;
        signed char* pB = pA + needA;
        pack_i32_to_i8<<<2048, 256, 0, stream>>>(q_x, (int*)pA, (int)(needA / 4));
        pack_i32_to_i8<<<1024, 256, 0, stream>>>(q_w, (int*)pB, (int)(needB / 4));
        int grid = (TOKENS / BM) * (OUT_F / BN);  // 32*16 = 512
        qgemm_i8<<<grid, 512, 0, stream>>>(pA, pB, bias, wscale, s_in, s_out, zp, out);
    } else {
        int total = TOKENS * OUT_F;
        qgemm_naive<<<(total + 255) / 256, 256, 0, stream>>>(q_x, q_w, bias, wscale, s_in, s_out, zp, out);
    }
}